// Round 3
// baseline (140.342 us; speedup 1.0000x reference)
//
#include <hip/hip_runtime.h>

#define IMG_H 512
#define IMG_W 512
#define NPLANES 24          // N*C = 8*3
#define ROWS_PER_BLK 16     // output rows per block
#define STRIPW 512          // full row width (one thread per column)
#define NITER 26            // ROWS_PER_BLK + 10 halo rows
#define NBLOCKS (32 * 24)
#define TOTAL_PIX 6291456.0f // 8*3*512*512

typedef float f32x2 __attribute__((ext_vector_type(2)));

// Gaussian window, sigma=1.5, K=11, normalized (matches jnp reference to ~1e-7)
__device__ __constant__ float GW[11] = {
    0.00102838f, 0.00759876f, 0.03600050f, 0.10935817f, 0.21300535f,
    0.26601172f, 0.21300535f, 0.10935817f, 0.03600050f, 0.00759876f,
    0.00102838f};

extern "C" __global__ __launch_bounds__(512) void ssim_structure_kernel(
    const float* __restrict__ x, const float* __restrict__ y,
    float* __restrict__ accum, unsigned int* __restrict__ counter,
    float* __restrict__ out) {
  const int tid = threadIdx.x;
  const int chunk = blockIdx.x;  // 0..31  (row chunk)
  const int plane = blockIdx.y;  // 0..23

  const size_t pbase = (size_t)plane * IMG_H * IMG_W;
  const float* __restrict__ xp = x + pbase;
  const float* __restrict__ yp = y + pbase;
  const int r0 = chunk * ROWS_PER_BLK;

  // double-buffered staging row: 522 needed (512 + 10 halo), pad to 528
  __shared__ f32x2 lrow[2][STRIPW + 16];

  // circular register buffers of horizontal sums, packed as (x,y) channel
  // pairs so the taps compile to v_pk_*_f32 (indices compile-time via the
  // unroll-by-11 trick below)
  f32x2 bm[11];   // (sum w*x,   sum w*y)
  f32x2 bq[11];   // (sum w*x*x, sum w*y*y)
  float bxy[11];  // sum w*x*y

  float acc = 0.0f;

  // ---- branch-free row loader: clamped addresses + 0/1 mask multiply ----
  const int gc = tid - 5;                            // main element column
  const int gcc = min(max(gc, 0), IMG_W - 1);        // clamped
  const float cmask = (gc >= 0 && gc < IMG_W) ? 1.0f : 0.0f;
  const int gc2 = gc + STRIPW;                       // halo column (tid < 10)
  const int gc2c = min(gc2, IMG_W - 1);              // gc2 >= 0 always
  const float hmask = (gc2 < IMG_W) ? 1.0f : 0.0f;

  f32x2 pre_m, pre_e;
  pre_m = (f32x2){0.f, 0.f};
  pre_e = (f32x2){0.f, 0.f};

  auto loadrow = [&](int i, f32x2& m, f32x2& e) {
    const int hr = r0 - 5 + i;
    // wave-uniform condition -> scalar branch
    if ((i < NITER) & (hr >= 0) & (hr < IMG_H)) {
      const int rowoff = hr * IMG_W;
      f32x2 v;
      v.x = xp[rowoff + gcc];
      v.y = yp[rowoff + gcc];
      m = v * cmask;
      if (tid < 10) {  // divergent only in wave 0
        f32x2 h;
        h.x = xp[rowoff + gc2c];
        h.y = yp[rowoff + gc2c];
        e = h * hmask;
      }
    } else {
      m = (f32x2){0.f, 0.f};
      e = (f32x2){0.f, 0.f};
    }
  };

  loadrow(0, pre_m, pre_e);

  for (int ob = 0; ob < 3; ++ob) {  // 3 * 11 = 33 slots (26 active)
#pragma unroll
    for (int ii = 0; ii < 11; ++ii) {
      const int i = ob * 11 + ii;
      if (i < NITER) {
        const int sel = i & 1;

        // stage prefetched row into LDS
        lrow[sel][tid] = pre_m;
        if (tid < 10) lrow[sel][STRIPW + tid] = pre_e;

        // issue next-row global loads BEFORE the barrier so they are in
        // flight while waves rendezvous
        loadrow(i + 1, pre_m, pre_e);

        __syncthreads();

        // horizontal pass -> circular slot ii (== i % 11), packed math:
        // per tap: v_pk_mul + v_pk_add + v_pk_fma + v_fma  (was 7 scalar)
        {
          f32x2 tm = {0.f, 0.f};
          f32x2 tq = {0.f, 0.f};
          float txy = 0.f;
#pragma unroll
          for (int d = 0; d < 11; ++d) {
            const f32x2 v = lrow[sel][tid + d];
            const float w = GW[d];
            const f32x2 wv = v * w;                       // (w*x, w*y)
            tm += wv;
            tq = __builtin_elementwise_fma(wv, v, tq);    // (w*x*x, w*y*y)
            txy = fmaf(wv.x, v.y, txy);
          }
          bm[ii] = tm;
          bq[ii] = tq;
          bxy[ii] = txy;
        }

        // vertical pass + epilogue for output row r0 + (i - 10)
        // per tap: 2x v_pk_fma + v_fma  (was 5 scalar)
        if (i >= 10) {
          f32x2 vm = {0.f, 0.f};
          f32x2 vq = {0.f, 0.f};
          float vxy = 0.f;
#pragma unroll
          for (int k = 0; k < 11; ++k) {
            const int s = (ii + 1 + k) % 11;  // compile-time after unroll
            const float w = GW[k];
            const f32x2 w2 = {w, w};
            vm = __builtin_elementwise_fma(bm[s], w2, vm);
            vq = __builtin_elementwise_fma(bq[s], w2, vq);
            vxy = fmaf(w, bxy[s], vxy);
          }
          const float sxy = fmaf(-vm.x, vm.y, vxy);
          f32x2 sp = __builtin_elementwise_fma(-vm, vm, vq);
          sp = __builtin_elementwise_max(sp, (f32x2){1e-12f, 1e-12f});
          const float denom = sqrtf(sp.x) * sqrtf(sp.y) + 1e-4f;
          acc += (sxy + 1e-4f) / denom;
        }
      }
    }
  }

  // ---- block reduction: wave shuffle then cross-wave LDS ----
#pragma unroll
  for (int off = 32; off > 0; off >>= 1) acc += __shfl_down(acc, off, 64);
  __shared__ float wsum[8];
  if ((tid & 63) == 0) wsum[tid >> 6] = acc;
  __syncthreads();
  if (tid == 0) {
    float bsum = 0.f;
#pragma unroll
    for (int w = 0; w < 8; ++w) bsum += wsum[w];
    atomicAdd(accum, bsum);
    __threadfence();
    const unsigned int ret = atomicAdd(counter, 1u);
    if (ret == (unsigned int)(NBLOCKS - 1)) {
      // all blocks' accum atomics are fenced-before their counter atomics,
      // so the running total is complete; atomic read bypasses stale caches
      __threadfence();
      const float total = atomicAdd(accum, 0.0f);
      out[0] = 1.0f - total * (1.0f / TOTAL_PIX);
    }
  }
}

extern "C" void kernel_launch(void* const* d_in, const int* in_sizes, int n_in,
                              void* d_out, int out_size, void* d_ws,
                              size_t ws_size, hipStream_t stream) {
  const float* x = (const float*)d_in[0];
  const float* y = (const float*)d_in[1];
  float* out = (float*)d_out;
  float* accum = (float*)d_ws;
  unsigned int* counter = (unsigned int*)((char*)d_ws + sizeof(float));

  hipMemsetAsync(d_ws, 0, 2 * sizeof(float), stream);

  dim3 grid(IMG_H / ROWS_PER_BLK, NPLANES);  // 32 x 24
  ssim_structure_kernel<<<grid, 512, 0, stream>>>(x, y, accum, counter, out);
}